// Round 22
// baseline (102.970 us; speedup 1.0000x reference)
//
#include <hip/hip_runtime.h>
#include <hip/hip_bf16.h>
#include <stdint.h>

#define DI __device__ __forceinline__

typedef __attribute__((ext_vector_type(8))) short short8;
typedef __attribute__((ext_vector_type(4))) float f32x4;

constexpr int CH   = 128;
constexpr int FH   = 120;
constexpr int FW   = 120;
constexpr int NBOX = 512;
constexpr int KDIM = 49 * 128;   // 6272
constexpr int D1   = 512;
constexpr int D2   = 256;
constexpr int SPLITS = 14;
constexpr int KC     = KDIM / SPLITS; // 448

DI float bf2f(uint32_t u16) { union { uint32_t i; float f; } v; v.i = u16 << 16; return v.f; }
DI float bf2f_hi(uint32_t u) { union { uint32_t i; float f; } v; v.i = u & 0xffff0000u; return v.f; }
DI uint16_t f2bf(float f) {
    __hip_bfloat16 h = __float2bfloat16(f);
    union { __hip_bfloat16 h; uint16_t u; } v; v.h = h; return v.u;
}

// ---------- K1: features [128,120,120] f32 -> ft [120,120,128] bf16 pairs ----------
__global__ __launch_bounds__(256) void k_preft(const float* __restrict__ f,
                                               uint32_t* __restrict__ ft) {
    __shared__ float lds[30 * 129];
    const int v = blockIdx.x, t = threadIdx.x;   // 480 blocks
    const int y = v >> 2, x0 = (v & 3) * 30;
    for (int e = t; e < 30 * 128; e += 256) {
        int c = e / 30, x = e - c * 30;
        lds[x * 129 + c] = f[c * (FH * FW) + y * FW + x0 + x];
    }
    __syncthreads();
    for (int e = t; e < 30 * 64; e += 256) {
        int x = e >> 6, cp = e & 63;
        float lo = lds[x * 129 + 2 * cp];
        float hi = lds[x * 129 + 2 * cp + 1];
        ft[(y * FW + x0 + x) * 64 + cp] = (uint32_t)f2bf(lo) | ((uint32_t)f2bf(hi) << 16);
    }
}

// ---------- ROI body v8: 4-corner lane split, 1 uint4 load per sample ----------
template<int GH, int GW>
DI void roi_body(const uint32_t* __restrict__ ft, uint32_t* __restrict__ A,
                 int wid, int lane,
                 const float (*__restrict__ tyv)[4], const float (*__restrict__ txv)[4],
                 int ph, int pw, float cnt) {
#pragma clang fp contract(off)
    const int q = lane >> 4, cg = lane & 15;
    const int qx = q & 1, qy = q >> 1;
    int offx[GW];
    float wx[GW];
#pragma unroll
    for (int j = 0; j < GW; ++j) {
        const float* e = txv[pw * 5 + j];
        wx[j]   = qx ? e[1] : e[0];
        offx[j] = __float_as_int(qx ? e[3] : e[2]) + 4 * cg;
    }
    int offy[GH];
    float wy[GH];
#pragma unroll
    for (int s = 0; s < GH; ++s) {
        const float* e = tyv[ph * 5 + s];
        wy[s]   = qy ? e[1] : e[0];
        offy[s] = __float_as_int(qy ? e[3] : e[2]);
    }

    float acc[8] = {};
    if constexpr (GH * GW <= 12) {
        uint4 u[GH][GW];
#pragma unroll
        for (int s = 0; s < GH; ++s)
#pragma unroll
            for (int j = 0; j < GW; ++j)
                u[s][j] = *(const uint4*)(ft + offy[s] + offx[j]);
#pragma unroll
        for (int s = 0; s < GH; ++s)
#pragma unroll
            for (int j = 0; j < GW; ++j) {
                const float w = wy[s] * wx[j];
                acc[0] += w * bf2f(u[s][j].x & 0xffffu); acc[1] += w * bf2f_hi(u[s][j].x);
                acc[2] += w * bf2f(u[s][j].y & 0xffffu); acc[3] += w * bf2f_hi(u[s][j].y);
                acc[4] += w * bf2f(u[s][j].z & 0xffffu); acc[5] += w * bf2f_hi(u[s][j].z);
                acc[6] += w * bf2f(u[s][j].w & 0xffffu); acc[7] += w * bf2f_hi(u[s][j].w);
            }
    } else {
#pragma unroll
        for (int s = 0; s < GH; ++s) {
            uint4 u[GW];
#pragma unroll
            for (int j = 0; j < GW; ++j)
                u[j] = *(const uint4*)(ft + offy[s] + offx[j]);
#pragma unroll
            for (int j = 0; j < GW; ++j) {
                const float w = wy[s] * wx[j];
                acc[0] += w * bf2f(u[j].x & 0xffffu); acc[1] += w * bf2f_hi(u[j].x);
                acc[2] += w * bf2f(u[j].y & 0xffffu); acc[3] += w * bf2f_hi(u[j].y);
                acc[4] += w * bf2f(u[j].z & 0xffffu); acc[5] += w * bf2f_hi(u[j].z);
                acc[6] += w * bf2f(u[j].w & 0xffffu); acc[7] += w * bf2f_hi(u[j].w);
            }
        }
    }
    float tot[8];
#pragma unroll
    for (int i = 0; i < 8; ++i) {
        float v16 = acc[i] + __shfl_xor(acc[i], 16);
        tot[i] = v16 + __shfl_xor(v16, 32);
    }
    if (q == 0) {
        uint4 pk;
        pk.x = (uint32_t)f2bf(tot[0] / cnt) | ((uint32_t)f2bf(tot[1] / cnt) << 16);
        pk.y = (uint32_t)f2bf(tot[2] / cnt) | ((uint32_t)f2bf(tot[3] / cnt) << 16);
        pk.z = (uint32_t)f2bf(tot[4] / cnt) | ((uint32_t)f2bf(tot[5] / cnt) << 16);
        pk.w = (uint32_t)f2bf(tot[6] / cnt) | ((uint32_t)f2bf(tot[7] / cnt) << 16);
        *(uint4*)(A + (size_t)wid * 64 + 4 * cg) = pk;
    }
}

// ---------- K2: ROI (6656 blk: box x 4-bin quad, LDS tables) + W1 (784) + W2 (32) ----------
__global__ __launch_bounds__(256) void k_roi_w(const uint32_t* __restrict__ ft,
                                               const float* __restrict__ boxes,
                                               const float* __restrict__ W1,
                                               const float* __restrict__ W2,
                                               uint32_t* __restrict__ A,
                                               uint16_t* __restrict__ W1rT,
                                               uint16_t* __restrict__ W2T) {
    __shared__ __align__(16) float lds[128 * 33];
    __shared__ __align__(16) float tyv[35][4];
    __shared__ __align__(16) float txv[35][4];
    const int blk = blockIdx.x, t = threadIdx.x;
    if (blk < 6656) {
#pragma clang fp contract(off)
        const int box = blk / 13, quad = blk % 13;
        const float bx = boxes[box * 4 + 0], by = boxes[box * 4 + 1];
        const float bw = boxes[box * 4 + 2], bh = boxes[box * 4 + 3];
        const float x1 = bx * 120.0f - 0.5f;
        const float y1 = by * 120.0f - 0.5f;
        const float roi_w = bw * 120.0f, roi_h = bh * 120.0f;
        const float bin_w = roi_w / 7.0f, bin_h = roi_h / 7.0f;
        const float gwf = fmaxf(ceilf(roi_w / 7.0f), 1.0f);
        const float ghf = fmaxf(ceilf(roi_h / 7.0f), 1.0f);
        const int gwi = (int)gwf, ghi = (int)ghf;
        const float cnt = ghf * gwf;

        if (t < 35) {
            const int ph = t / 5, sy = t % 5;
            float yy = (y1 + (float)ph * bin_h) + ((float)sy + 0.5f) * bin_h / ghf;
            float my = ((yy > -1.0f) && (yy < 120.0f)) ? 1.0f : 0.0f;
            float yc = fminf(fmaxf(yy, 0.0f), 119.0f);
            int y0 = (int)floorf(yc);
            int yh = min(y0 + 1, 119);
            float ly = yc - (float)y0, hy = 1.0f - ly;
            tyv[t][0] = hy * my;
            tyv[t][1] = ly * my;
            tyv[t][2] = __int_as_float(y0 * (FW * 64));
            tyv[t][3] = __int_as_float(yh * (FW * 64));
        } else if (t < 70) {
            const int u = t - 35;
            const int pw = u / 5, sx = u % 5;
            float xx = (x1 + (float)pw * bin_w) + ((float)sx + 0.5f) * bin_w / gwf;
            float mx = ((xx > -1.0f) && (xx < 120.0f)) ? 1.0f : 0.0f;
            float xc = fminf(fmaxf(xx, 0.0f), 119.0f);
            int x0 = (int)floorf(xc);
            int xh = min(x0 + 1, 119);
            float lx = xc - (float)x0, hx = 1.0f - lx;
            txv[u][0] = hx * mx;
            txv[u][1] = lx * mx;
            txv[u][2] = __int_as_float(x0 * 64);
            txv[u][3] = __int_as_float(xh * 64);
        }
        __syncthreads();

        const int w8 = t >> 6, lane = t & 63;
        const int bin = quad * 4 + w8;
        if (bin < 49) {
            const int ph = bin / 7, pw = bin - ph * 7;
            const int wid = box * 49 + bin;
#define RB(GH, GW) roi_body<GH, GW>(ft, A, wid, lane, tyv, txv, ph, pw, cnt)
            switch (ghi * 8 + gwi) {
            case  9: RB(1,1); break; case 10: RB(1,2); break; case 11: RB(1,3); break;
            case 12: RB(1,4); break; case 13: RB(1,5); break;
            case 17: RB(2,1); break; case 18: RB(2,2); break; case 19: RB(2,3); break;
            case 20: RB(2,4); break; case 21: RB(2,5); break;
            case 25: RB(3,1); break; case 26: RB(3,2); break; case 27: RB(3,3); break;
            case 28: RB(3,4); break; case 29: RB(3,5); break;
            case 33: RB(4,1); break; case 34: RB(4,2); break; case 35: RB(4,3); break;
            case 36: RB(4,4); break; case 37: RB(4,5); break;
            case 41: RB(5,1); break; case 42: RB(5,2); break; case 43: RB(5,3); break;
            case 44: RB(5,4); break; default: RB(5,5); break;
            }
#undef RB
        }
    } else if (blk < 7440) {
        const int vb = blk - 6656;              // 0..783
        const int b = vb % 49, j0 = (vb / 49) * 32;
        for (int e = t; e < 4096; e += 256) {
            int ci = e >> 5, jj = e & 31;
            lds[ci * 33 + jj] = W1[(ci * 49 + b) * D1 + j0 + jj];
        }
        __syncthreads();
        for (int e = t; e < 4096; e += 256) {
            int jj = e >> 7, ci = e & 127;
            W1rT[(size_t)(j0 + jj) * KDIM + b * 128 + ci] = f2bf(lds[ci * 33 + jj]);
        }
    } else {
        const int v2 = blk - 7440;              // 0..31
        const int n0 = (v2 & 7) * 32, k0 = (v2 >> 3) * 128;
        for (int e = t; e < 4096; e += 256) {
            int k = e >> 5, nn = e & 31;
            lds[k * 33 + nn] = W2[(k0 + k) * D2 + n0 + nn];
        }
        __syncthreads();
        for (int e = t; e < 4096; e += 256) {
            int nn = e >> 7, k = e & 127;
            W2T[(n0 + nn) * D1 + k0 + k] = f2bf(lds[k * 33 + nn]);
        }
    }
}

// ---------- K3: GEMM1 split-K, 64x64 tiles, XCD-chunked block swizzle (R18 best) ----------
__global__ __launch_bounds__(256) void k_gemm1(const uint16_t* __restrict__ A,
                                               const uint16_t* __restrict__ B,
                                               float* __restrict__ P) {
    __shared__ __align__(16) uint16_t As[64 * 32];
    __shared__ __align__(16) uint16_t Bs[64 * 32];
    const int id = blockIdx.x;                 // 0..895
    const int nid = (id & 7) * 112 + (id >> 3);
    const int bz = nid >> 6;                   // z-slice 0..13
    const int r64 = nid & 63;
    const int m0 = (r64 >> 3) * 64, n0 = (r64 & 7) * 64;
    const int kbase = bz * KC;
    const int t = threadIdx.x;
    const int lane = t & 63, w = t >> 6;
    const int wr = w >> 1, wc = w & 1;

    f32x4 acc[2][2] = {};
    const int kb = lane >> 4, r16 = lane & 15;
    const int row = t >> 2, c8 = t & 3;
    const int ldst = row * 32 + ((c8 ^ ((row >> 1) & 3)) * 8);
    const uint16_t* ga = A + (size_t)(m0 + row) * KDIM + c8 * 8;
    const uint16_t* gb = B + (size_t)(n0 + row) * KDIM + c8 * 8;

    for (int ks = 0; ks < KC / 32; ++ks) {
        const int kk = kbase + ks * 32;
        __syncthreads();
        *(uint4*)&As[ldst] = *(const uint4*)&ga[kk];
        *(uint4*)&Bs[ldst] = *(const uint4*)&gb[kk];
        __syncthreads();

        short8 af[2], bfr[2];
#pragma unroll
        for (int mi = 0; mi < 2; ++mi) {
            int ar = wr * 32 + mi * 16 + r16;
            af[mi] = *(const short8*)&As[ar * 32 + (kb ^ ((ar >> 1) & 3)) * 8];
        }
#pragma unroll
        for (int ni = 0; ni < 2; ++ni) {
            int br = wc * 32 + ni * 16 + r16;
            bfr[ni] = *(const short8*)&Bs[br * 32 + (kb ^ ((br >> 1) & 3)) * 8];
        }
#pragma unroll
        for (int mi = 0; mi < 2; ++mi)
#pragma unroll
            for (int ni = 0; ni < 2; ++ni)
                acc[mi][ni] = __builtin_amdgcn_mfma_f32_16x16x32_bf16(af[mi], bfr[ni], acc[mi][ni], 0, 0, 0);
    }

    float* outp = P + (size_t)bz * (D1 * D1);
#pragma unroll
    for (int mi = 0; mi < 2; ++mi)
#pragma unroll
        for (int ni = 0; ni < 2; ++ni) {
            int rrow = m0 + wr * 32 + mi * 16 + kb * 4;
            int ccol = n0 + wc * 32 + ni * 16 + r16;
#pragma unroll
            for (int r = 0; r < 4; ++r)
                outp[(size_t)(rrow + r) * D1 + ccol] = acc[mi][ni][r];
        }
}

// ---------- K4: reduce split-K + bias + ReLU -> H bf16, full-machine grid ----------
__global__ __launch_bounds__(256) void k_reduce1(const float* __restrict__ P,
                                                 const float* __restrict__ b1,
                                                 uint16_t* __restrict__ Hm) {
    const int e4 = blockIdx.x * 256 + threadIdx.x;  // 65536 f32x4 groups
    const f32x4* P4 = (const f32x4*)P;
    f32x4 s = {};
#pragma unroll
    for (int i = 0; i < SPLITS; ++i) s += P4[(size_t)i * (D1 * D1 / 4) + e4];
    const int c4 = (e4 & 127) * 4;
    uint16_t h[4];
#pragma unroll
    for (int j = 0; j < 4; ++j) h[j] = f2bf(fmaxf(s[j] + b1[c4 + j], 0.0f));
    uint2 pk;
    pk.x = (uint32_t)h[0] | ((uint32_t)h[1] << 16);
    pk.y = (uint32_t)h[2] | ((uint32_t)h[3] << 16);
    *(uint2*)&Hm[(size_t)e4 * 4] = pk;
}

// ---------- K5: GEMM2 (proven thin version) ----------
__global__ __launch_bounds__(256) void k_gemm2(const uint16_t* __restrict__ Hm,
                                               const uint16_t* __restrict__ W2T,
                                               const float* __restrict__ b2,
                                               float* __restrict__ out) {
    const int wid  = blockIdx.x * 4 + (threadIdx.x >> 6); // 0..511
    const int lane = threadIdx.x & 63;
    const int mt = wid >> 4, nt = wid & 15;
    const int m0 = mt * 16, n0 = nt * 16;
    const int g = lane >> 4, i = lane & 15;
    f32x4 acc = {};
#pragma unroll
    for (int kk = 0; kk < D1 / 32; ++kk) {
        short8 a = *(const short8*)&Hm[(m0 + i) * D1 + kk * 32 + g * 8];
        short8 b = *(const short8*)&W2T[(n0 + i) * D1 + kk * 32 + g * 8];
        acc = __builtin_amdgcn_mfma_f32_16x16x32_bf16(a, b, acc, 0, 0, 0);
    }
    const float bias = b2[n0 + i];
#pragma unroll
    for (int r = 0; r < 4; ++r)
        out[(size_t)(m0 + g * 4 + r) * D2 + n0 + i] = acc[r] + bias;
}

extern "C" void kernel_launch(void* const* d_in, const int* in_sizes, int n_in,
                              void* d_out, int out_size, void* d_ws, size_t ws_size,
                              hipStream_t stream) {
    const float* f     = (const float*)d_in[0];
    const float* boxes = (const float*)d_in[1];
    const float* W1    = (const float*)d_in[2];
    const float* b1    = (const float*)d_in[3];
    const float* W2    = (const float*)d_in[4];
    const float* b2    = (const float*)d_in[5];
    float* out = (float*)d_out;

    char* p = (char*)d_ws;
    uint32_t* ft   = (uint32_t*)p; p += (size_t)FH * FW * (CH / 2) * 4;  // 3.7 MB
    uint16_t* W1rT = (uint16_t*)p; p += (size_t)D1 * KDIM * 2;           // 6.4 MB
    uint16_t* W2T  = (uint16_t*)p; p += (size_t)D2 * D1 * 2;             // 0.26 MB
    uint16_t* Ar   = (uint16_t*)p; p += (size_t)NBOX * KDIM * 2;         // 6.4 MB
    float*    Pp   = (float*)p;    p += (size_t)SPLITS * D1 * D1 * 4;    // 14.7 MB
    uint16_t* Hm   = (uint16_t*)p; p += (size_t)D1 * D1 * 2;             // 0.52 MB

    k_preft<<<480, 256, 0, stream>>>(f, ft);
    k_roi_w<<<7472, 256, 0, stream>>>(ft, boxes, W1, W2, (uint32_t*)Ar, W1rT, W2T);
    // MEASUREMENT: k_gemm1 is idempotent; 5 launches make t_gemm1 visible as
    // dur = base(60.7) + 4*(t_g1 + gap), same technique that pinned t_roi (R17).
    for (int rep = 0; rep < 5; ++rep)
        k_gemm1<<<896, 256, 0, stream>>>(Ar, W1rT, Pp);
    k_reduce1<<<D1 * D1 / 4 / 256, 256, 0, stream>>>(Pp, b1, Hm);
    k_gemm2<<<(D1 / 16) * (D2 / 16) / 4, 256, 0, stream>>>(Hm, W2T, b2, out);
}

// Round 23
// 58.925 us; speedup vs baseline: 1.7475x; 1.7475x over previous
//
#include <hip/hip_runtime.h>
#include <hip/hip_bf16.h>
#include <stdint.h>

#define DI __device__ __forceinline__

typedef __attribute__((ext_vector_type(8))) short short8;
typedef __attribute__((ext_vector_type(4))) float f32x4;

constexpr int CH   = 128;
constexpr int FH   = 120;
constexpr int FW   = 120;
constexpr int NBOX = 512;
constexpr int KDIM = 49 * 128;   // 6272
constexpr int D1   = 512;
constexpr int D2   = 256;
constexpr int SPLITS = 14;
constexpr int KC     = KDIM / SPLITS; // 448

DI float bf2f(uint32_t u16) { union { uint32_t i; float f; } v; v.i = u16 << 16; return v.f; }
DI float bf2f_hi(uint32_t u) { union { uint32_t i; float f; } v; v.i = u & 0xffff0000u; return v.f; }
DI uint16_t f2bf(float f) {
    __hip_bfloat16 h = __float2bfloat16(f);
    union { __hip_bfloat16 h; uint16_t u; } v; v.h = h; return v.u;
}

// ---------- K1: features [128,120,120] f32 -> ft [120,120,128] bf16 pairs ----------
__global__ __launch_bounds__(256) void k_preft(const float* __restrict__ f,
                                               uint32_t* __restrict__ ft) {
    __shared__ float lds[30 * 129];
    const int v = blockIdx.x, t = threadIdx.x;   // 480 blocks
    const int y = v >> 2, x0 = (v & 3) * 30;
    for (int e = t; e < 30 * 128; e += 256) {
        int c = e / 30, x = e - c * 30;
        lds[x * 129 + c] = f[c * (FH * FW) + y * FW + x0 + x];
    }
    __syncthreads();
    for (int e = t; e < 30 * 64; e += 256) {
        int x = e >> 6, cp = e & 63;
        float lo = lds[x * 129 + 2 * cp];
        float hi = lds[x * 129 + 2 * cp + 1];
        ft[(y * FW + x0 + x) * 64 + cp] = (uint32_t)f2bf(lo) | ((uint32_t)f2bf(hi) << 16);
    }
}

// ---------- ROI body v8: 4-corner lane split, 1 uint4 load per sample ----------
template<int GH, int GW>
DI void roi_body(const uint32_t* __restrict__ ft, uint32_t* __restrict__ A,
                 int wid, int lane,
                 const float (*__restrict__ tyv)[4], const float (*__restrict__ txv)[4],
                 int ph, int pw, float cnt) {
#pragma clang fp contract(off)
    const int q = lane >> 4, cg = lane & 15;
    const int qx = q & 1, qy = q >> 1;
    int offx[GW];
    float wx[GW];
#pragma unroll
    for (int j = 0; j < GW; ++j) {
        const float* e = txv[pw * 5 + j];
        wx[j]   = qx ? e[1] : e[0];
        offx[j] = __float_as_int(qx ? e[3] : e[2]) + 4 * cg;
    }
    int offy[GH];
    float wy[GH];
#pragma unroll
    for (int s = 0; s < GH; ++s) {
        const float* e = tyv[ph * 5 + s];
        wy[s]   = qy ? e[1] : e[0];
        offy[s] = __float_as_int(qy ? e[3] : e[2]);
    }

    float acc[8] = {};
    if constexpr (GH * GW <= 12) {
        uint4 u[GH][GW];
#pragma unroll
        for (int s = 0; s < GH; ++s)
#pragma unroll
            for (int j = 0; j < GW; ++j)
                u[s][j] = *(const uint4*)(ft + offy[s] + offx[j]);
#pragma unroll
        for (int s = 0; s < GH; ++s)
#pragma unroll
            for (int j = 0; j < GW; ++j) {
                const float w = wy[s] * wx[j];
                acc[0] += w * bf2f(u[s][j].x & 0xffffu); acc[1] += w * bf2f_hi(u[s][j].x);
                acc[2] += w * bf2f(u[s][j].y & 0xffffu); acc[3] += w * bf2f_hi(u[s][j].y);
                acc[4] += w * bf2f(u[s][j].z & 0xffffu); acc[5] += w * bf2f_hi(u[s][j].z);
                acc[6] += w * bf2f(u[s][j].w & 0xffffu); acc[7] += w * bf2f_hi(u[s][j].w);
            }
    } else {
#pragma unroll
        for (int s = 0; s < GH; ++s) {
            uint4 u[GW];
#pragma unroll
            for (int j = 0; j < GW; ++j)
                u[j] = *(const uint4*)(ft + offy[s] + offx[j]);
#pragma unroll
            for (int j = 0; j < GW; ++j) {
                const float w = wy[s] * wx[j];
                acc[0] += w * bf2f(u[j].x & 0xffffu); acc[1] += w * bf2f_hi(u[j].x);
                acc[2] += w * bf2f(u[j].y & 0xffffu); acc[3] += w * bf2f_hi(u[j].y);
                acc[4] += w * bf2f(u[j].z & 0xffffu); acc[5] += w * bf2f_hi(u[j].z);
                acc[6] += w * bf2f(u[j].w & 0xffffu); acc[7] += w * bf2f_hi(u[j].w);
            }
        }
    }
    float tot[8];
#pragma unroll
    for (int i = 0; i < 8; ++i) {
        float v16 = acc[i] + __shfl_xor(acc[i], 16);
        tot[i] = v16 + __shfl_xor(v16, 32);
    }
    if (q == 0) {
        uint4 pk;
        pk.x = (uint32_t)f2bf(tot[0] / cnt) | ((uint32_t)f2bf(tot[1] / cnt) << 16);
        pk.y = (uint32_t)f2bf(tot[2] / cnt) | ((uint32_t)f2bf(tot[3] / cnt) << 16);
        pk.z = (uint32_t)f2bf(tot[4] / cnt) | ((uint32_t)f2bf(tot[5] / cnt) << 16);
        pk.w = (uint32_t)f2bf(tot[6] / cnt) | ((uint32_t)f2bf(tot[7] / cnt) << 16);
        *(uint4*)(A + (size_t)wid * 64 + 4 * cg) = pk;
    }
}

// ---------- K2: ROI (6656 blk: box x 4-bin quad, LDS tables) + W1 (784) + W2 (32) ----------
__global__ __launch_bounds__(256) void k_roi_w(const uint32_t* __restrict__ ft,
                                               const float* __restrict__ boxes,
                                               const float* __restrict__ W1,
                                               const float* __restrict__ W2,
                                               uint32_t* __restrict__ A,
                                               uint16_t* __restrict__ W1rT,
                                               uint16_t* __restrict__ W2T) {
    __shared__ __align__(16) float lds[128 * 33];
    __shared__ __align__(16) float tyv[35][4];
    __shared__ __align__(16) float txv[35][4];
    const int blk = blockIdx.x, t = threadIdx.x;
    if (blk < 6656) {
#pragma clang fp contract(off)
        const int box = blk / 13, quad = blk % 13;
        const float bx = boxes[box * 4 + 0], by = boxes[box * 4 + 1];
        const float bw = boxes[box * 4 + 2], bh = boxes[box * 4 + 3];
        const float x1 = bx * 120.0f - 0.5f;
        const float y1 = by * 120.0f - 0.5f;
        const float roi_w = bw * 120.0f, roi_h = bh * 120.0f;
        const float bin_w = roi_w / 7.0f, bin_h = roi_h / 7.0f;
        const float gwf = fmaxf(ceilf(roi_w / 7.0f), 1.0f);
        const float ghf = fmaxf(ceilf(roi_h / 7.0f), 1.0f);
        const int gwi = (int)gwf, ghi = (int)ghf;
        const float cnt = ghf * gwf;

        if (t < 35) {
            const int ph = t / 5, sy = t % 5;
            float yy = (y1 + (float)ph * bin_h) + ((float)sy + 0.5f) * bin_h / ghf;
            float my = ((yy > -1.0f) && (yy < 120.0f)) ? 1.0f : 0.0f;
            float yc = fminf(fmaxf(yy, 0.0f), 119.0f);
            int y0 = (int)floorf(yc);
            int yh = min(y0 + 1, 119);
            float ly = yc - (float)y0, hy = 1.0f - ly;
            tyv[t][0] = hy * my;
            tyv[t][1] = ly * my;
            tyv[t][2] = __int_as_float(y0 * (FW * 64));
            tyv[t][3] = __int_as_float(yh * (FW * 64));
        } else if (t < 70) {
            const int u = t - 35;
            const int pw = u / 5, sx = u % 5;
            float xx = (x1 + (float)pw * bin_w) + ((float)sx + 0.5f) * bin_w / gwf;
            float mx = ((xx > -1.0f) && (xx < 120.0f)) ? 1.0f : 0.0f;
            float xc = fminf(fmaxf(xx, 0.0f), 119.0f);
            int x0 = (int)floorf(xc);
            int xh = min(x0 + 1, 119);
            float lx = xc - (float)x0, hx = 1.0f - lx;
            txv[u][0] = hx * mx;
            txv[u][1] = lx * mx;
            txv[u][2] = __int_as_float(x0 * 64);
            txv[u][3] = __int_as_float(xh * 64);
        }
        __syncthreads();

        const int w8 = t >> 6, lane = t & 63;
        const int bin = quad * 4 + w8;
        if (bin < 49) {
            const int ph = bin / 7, pw = bin - ph * 7;
            const int wid = box * 49 + bin;
#define RB(GH, GW) roi_body<GH, GW>(ft, A, wid, lane, tyv, txv, ph, pw, cnt)
            switch (ghi * 8 + gwi) {
            case  9: RB(1,1); break; case 10: RB(1,2); break; case 11: RB(1,3); break;
            case 12: RB(1,4); break; case 13: RB(1,5); break;
            case 17: RB(2,1); break; case 18: RB(2,2); break; case 19: RB(2,3); break;
            case 20: RB(2,4); break; case 21: RB(2,5); break;
            case 25: RB(3,1); break; case 26: RB(3,2); break; case 27: RB(3,3); break;
            case 28: RB(3,4); break; case 29: RB(3,5); break;
            case 33: RB(4,1); break; case 34: RB(4,2); break; case 35: RB(4,3); break;
            case 36: RB(4,4); break; case 37: RB(4,5); break;
            case 41: RB(5,1); break; case 42: RB(5,2); break; case 43: RB(5,3); break;
            case 44: RB(5,4); break; default: RB(5,5); break;
            }
#undef RB
        }
    } else if (blk < 7440) {
        const int vb = blk - 6656;              // 0..783
        const int b = vb % 49, j0 = (vb / 49) * 32;
        for (int e = t; e < 4096; e += 256) {
            int ci = e >> 5, jj = e & 31;
            lds[ci * 33 + jj] = W1[(ci * 49 + b) * D1 + j0 + jj];
        }
        __syncthreads();
        for (int e = t; e < 4096; e += 256) {
            int jj = e >> 7, ci = e & 127;
            W1rT[(size_t)(j0 + jj) * KDIM + b * 128 + ci] = f2bf(lds[ci * 33 + jj]);
        }
    } else {
        const int v2 = blk - 7440;              // 0..31
        const int n0 = (v2 & 7) * 32, k0 = (v2 >> 3) * 128;
        for (int e = t; e < 4096; e += 256) {
            int k = e >> 5, nn = e & 31;
            lds[k * 33 + nn] = W2[(k0 + k) * D2 + n0 + nn];
        }
        __syncthreads();
        for (int e = t; e < 4096; e += 256) {
            int nn = e >> 7, k = e & 127;
            W2T[(n0 + nn) * D1 + k0 + k] = f2bf(lds[k * 33 + nn]);
        }
    }
}

// ---------- K3: GEMM1 split-K, 64x64 tiles, XCD-chunked; partials stored bf16 ----------
__global__ __launch_bounds__(256) void k_gemm1(const uint16_t* __restrict__ A,
                                               const uint16_t* __restrict__ B,
                                               uint16_t* __restrict__ Pb) {
    __shared__ __align__(16) uint16_t As[64 * 32];
    __shared__ __align__(16) uint16_t Bs[64 * 32];
    const int id = blockIdx.x;                 // 0..895
    const int nid = (id & 7) * 112 + (id >> 3);
    const int bz = nid >> 6;                   // z-slice 0..13
    const int r64 = nid & 63;
    const int m0 = (r64 >> 3) * 64, n0 = (r64 & 7) * 64;
    const int kbase = bz * KC;
    const int t = threadIdx.x;
    const int lane = t & 63, w = t >> 6;
    const int wr = w >> 1, wc = w & 1;

    f32x4 acc[2][2] = {};
    const int kb = lane >> 4, r16 = lane & 15;
    const int row = t >> 2, c8 = t & 3;
    const int ldst = row * 32 + ((c8 ^ ((row >> 1) & 3)) * 8);
    const uint16_t* ga = A + (size_t)(m0 + row) * KDIM + c8 * 8;
    const uint16_t* gb = B + (size_t)(n0 + row) * KDIM + c8 * 8;

    for (int ks = 0; ks < KC / 32; ++ks) {
        const int kk = kbase + ks * 32;
        __syncthreads();
        *(uint4*)&As[ldst] = *(const uint4*)&ga[kk];
        *(uint4*)&Bs[ldst] = *(const uint4*)&gb[kk];
        __syncthreads();

        short8 af[2], bfr[2];
#pragma unroll
        for (int mi = 0; mi < 2; ++mi) {
            int ar = wr * 32 + mi * 16 + r16;
            af[mi] = *(const short8*)&As[ar * 32 + (kb ^ ((ar >> 1) & 3)) * 8];
        }
#pragma unroll
        for (int ni = 0; ni < 2; ++ni) {
            int br = wc * 32 + ni * 16 + r16;
            bfr[ni] = *(const short8*)&Bs[br * 32 + (kb ^ ((br >> 1) & 3)) * 8];
        }
#pragma unroll
        for (int mi = 0; mi < 2; ++mi)
#pragma unroll
            for (int ni = 0; ni < 2; ++ni)
                acc[mi][ni] = __builtin_amdgcn_mfma_f32_16x16x32_bf16(af[mi], bfr[ni], acc[mi][ni], 0, 0, 0);
    }

    uint16_t* outp = Pb + (size_t)bz * (D1 * D1);
#pragma unroll
    for (int mi = 0; mi < 2; ++mi)
#pragma unroll
        for (int ni = 0; ni < 2; ++ni) {
            int rrow = m0 + wr * 32 + mi * 16 + kb * 4;
            int ccol = n0 + wc * 32 + ni * 16 + r16;
#pragma unroll
            for (int r = 0; r < 4; ++r)
                outp[(size_t)(rrow + r) * D1 + ccol] = f2bf(acc[mi][ni][r]);
        }
}

// ---------- K4: reduce bf16 split-K + bias + ReLU -> H bf16, full-machine grid ----------
__global__ __launch_bounds__(256) void k_reduce1(const uint16_t* __restrict__ Pb,
                                                 const float* __restrict__ b1,
                                                 uint16_t* __restrict__ Hm) {
    const int e4 = blockIdx.x * 256 + threadIdx.x;  // 65536 groups of 4 elems
    const uint2* P2 = (const uint2*)Pb;             // 4 bf16 per uint2
    float s0 = 0.f, s1 = 0.f, s2 = 0.f, s3 = 0.f;
#pragma unroll
    for (int i = 0; i < SPLITS; ++i) {
        uint2 q = P2[(size_t)i * (D1 * D1 / 4) + e4];
        s0 += bf2f(q.x & 0xffffu); s1 += bf2f_hi(q.x);
        s2 += bf2f(q.y & 0xffffu); s3 += bf2f_hi(q.y);
    }
    const int c4 = (e4 & 127) * 4;
    uint16_t h0 = f2bf(fmaxf(s0 + b1[c4 + 0], 0.0f));
    uint16_t h1 = f2bf(fmaxf(s1 + b1[c4 + 1], 0.0f));
    uint16_t h2 = f2bf(fmaxf(s2 + b1[c4 + 2], 0.0f));
    uint16_t h3 = f2bf(fmaxf(s3 + b1[c4 + 3], 0.0f));
    uint2 pk;
    pk.x = (uint32_t)h0 | ((uint32_t)h1 << 16);
    pk.y = (uint32_t)h2 | ((uint32_t)h3 << 16);
    *(uint2*)&Hm[(size_t)e4 * 4] = pk;
}

// ---------- K5: GEMM2 (proven thin version) ----------
__global__ __launch_bounds__(256) void k_gemm2(const uint16_t* __restrict__ Hm,
                                               const uint16_t* __restrict__ W2T,
                                               const float* __restrict__ b2,
                                               float* __restrict__ out) {
    const int wid  = blockIdx.x * 4 + (threadIdx.x >> 6); // 0..511
    const int lane = threadIdx.x & 63;
    const int mt = wid >> 4, nt = wid & 15;
    const int m0 = mt * 16, n0 = nt * 16;
    const int g = lane >> 4, i = lane & 15;
    f32x4 acc = {};
#pragma unroll
    for (int kk = 0; kk < D1 / 32; ++kk) {
        short8 a = *(const short8*)&Hm[(m0 + i) * D1 + kk * 32 + g * 8];
        short8 b = *(const short8*)&W2T[(n0 + i) * D1 + kk * 32 + g * 8];
        acc = __builtin_amdgcn_mfma_f32_16x16x32_bf16(a, b, acc, 0, 0, 0);
    }
    const float bias = b2[n0 + i];
#pragma unroll
    for (int r = 0; r < 4; ++r)
        out[(size_t)(m0 + g * 4 + r) * D2 + n0 + i] = acc[r] + bias;
}

extern "C" void kernel_launch(void* const* d_in, const int* in_sizes, int n_in,
                              void* d_out, int out_size, void* d_ws, size_t ws_size,
                              hipStream_t stream) {
    const float* f     = (const float*)d_in[0];
    const float* boxes = (const float*)d_in[1];
    const float* W1    = (const float*)d_in[2];
    const float* b1    = (const float*)d_in[3];
    const float* W2    = (const float*)d_in[4];
    const float* b2    = (const float*)d_in[5];
    float* out = (float*)d_out;

    char* p = (char*)d_ws;
    uint32_t* ft   = (uint32_t*)p; p += (size_t)FH * FW * (CH / 2) * 4;  // 3.7 MB
    uint16_t* W1rT = (uint16_t*)p; p += (size_t)D1 * KDIM * 2;           // 6.4 MB
    uint16_t* W2T  = (uint16_t*)p; p += (size_t)D2 * D1 * 2;             // 0.26 MB
    uint16_t* Ar   = (uint16_t*)p; p += (size_t)NBOX * KDIM * 2;         // 6.4 MB
    uint16_t* Pb   = (uint16_t*)p; p += (size_t)SPLITS * D1 * D1 * 2;    // 7.3 MB
    uint16_t* Hm   = (uint16_t*)p; p += (size_t)D1 * D1 * 2;             // 0.52 MB

    k_preft<<<480, 256, 0, stream>>>(f, ft);
    k_roi_w<<<7472, 256, 0, stream>>>(ft, boxes, W1, W2, (uint32_t*)Ar, W1rT, W2T);
    k_gemm1<<<896, 256, 0, stream>>>(Ar, W1rT, Pb);
    k_reduce1<<<D1 * D1 / 4 / 256, 256, 0, stream>>>(Pb, b1, Hm);
    k_gemm2<<<(D1 / 16) * (D2 / 16) / 4, 256, 0, stream>>>(Hm, W2T, b2, out);
}